// Round 3
// baseline (455.999 us; speedup 1.0000x reference)
//
#include <hip/hip_runtime.h>
#include <hip/hip_bf16.h>
#include <math.h>

#define T_  256
#define B_  32
#define V_  36
#define D_  128
#define H_  4
#define DK_ 32
#define S_  16
#define D4_ 512
#define K1_ 4608   // V_*D_
#define M_  8192   // B_*T_

typedef __hip_bfloat16 bf16;
typedef __attribute__((ext_vector_type(8))) short short8;
typedef __attribute__((ext_vector_type(4))) float f32x4;

__device__ __forceinline__ float gelu_f(float x){
    return 0.5f * x * (1.0f + erff(x * 0.70710678118654752f));
}

__device__ __forceinline__ unsigned short bf16_bits(float x){
    bf16 h = __float2bfloat16(x);
    return *reinterpret_cast<unsigned short*>(&h);
}

#define GLD16(g, l) __builtin_amdgcn_global_load_lds( \
    (const __attribute__((address_space(1))) void*)(g), \
    (__attribute__((address_space(3))) void*)(l), 16, 0, 0)

// ---------------------------------------------------------------- PE[(b,t),dd]
__global__ void k_pe(const float* __restrict__ Xtimes, float* __restrict__ PE){
    int bt = blockIdx.x;            // b*T_+t
    int b = bt >> 8, t = bt & 255;
    int dd = threadIdx.x;           // 0..127
    float x = Xtimes[t*B_ + b];
    int i = (dd < 64) ? dd : dd - 64;
    // 1/timescale = 500^(-i/63) = exp2(-i * log2(500)/63)
    float sc = x * exp2f(-(float)i * (8.965784284662087f / 63.0f));
    PE[(size_t)bt*D_ + dd] = (dd < 64) ? sinf(sc) : cosf(sc);
}

// ---------------------------------------------- CB[b,v,dd] = temp_b + emb(b,v,dd)
__global__ void k_cb(const float* __restrict__ Xstatic, const float* __restrict__ embW,
                     const float* __restrict__ embB, const float* __restrict__ tempB,
                     float* __restrict__ CB){
    int bv = blockIdx.x;            // b*V_+v
    int b = bv / V_, v = bv - (bv / V_) * V_;
    int dd = threadIdx.x;
    int c = v*D_ + dd;
    float acc = tempB[c] + embB[c];
    #pragma unroll
    for(int s = 0; s < S_; ++s) acc = fmaf(Xstatic[b*S_+s], embW[s*K1_ + c], acc);
    CB[(size_t)bv*D_ + dd] = acc;
}

// ---------------- per (b,v): sm, sx, sp; H4 = (sx*temp_w + sm*CB + sp)/(sm+1)
__global__ void k_h4(const float* __restrict__ Xtemp, const int* __restrict__ mask,
                     const float* __restrict__ PE, const float* __restrict__ tempW,
                     const float* __restrict__ CB, float* __restrict__ H4){
    __shared__ float s_m[T_];
    __shared__ float s_r0[256];
    __shared__ float s_r1[256];
    __shared__ float s_p[2][D_];
    int bv = blockIdx.x;
    int b = bv / V_, v = bv - (bv / V_) * V_;
    int tid = threadIdx.x;          // = t
    float mval = (float)mask[(tid*B_ + b)*V_ + v];
    float xval = Xtemp[(tid*B_ + b)*V_ + v];
    s_m[tid]  = mval;
    s_r0[tid] = mval;
    s_r1[tid] = mval * xval;
    __syncthreads();
    for(int off = 128; off > 0; off >>= 1){
        if(tid < off){ s_r0[tid] += s_r0[tid+off]; s_r1[tid] += s_r1[tid+off]; }
        __syncthreads();
    }
    float sm = s_r0[0], sx = s_r1[0];
    int dd = tid & 127, half = tid >> 7;
    float sp = 0.f;
    for(int tt = half*128; tt < half*128 + 128; ++tt)
        sp = fmaf(s_m[tt], PE[(size_t)(b*T_ + tt)*D_ + dd], sp);
    s_p[half][dd] = sp;
    __syncthreads();
    if(tid < D_){
        float spv = s_p[0][tid] + s_p[1][tid];
        float h2 = fmaf(sx, tempW[v*D_ + tid], fmaf(sm, CB[(size_t)bv*D_ + tid], spv));
        H4[(size_t)bv*D_ + tid] = h2 / (sm + 1.0f);
    }
}

// ---------------------------------------------- q,k (scaled), mean_v per (b,v)
__global__ void k_qkv(const float* __restrict__ H4, const float* __restrict__ Wq,
                      const float* __restrict__ Wk, const float* __restrict__ Wv,
                      float* __restrict__ QS, float* __restrict__ KS, float* __restrict__ MV){
    __shared__ float s_h[D_];
    int bv = blockIdx.x;
    int o = threadIdx.x;
    s_h[o] = H4[(size_t)bv*D_ + o];
    __syncthreads();
    float aq = 0.f, ak = 0.f, av = 0.f;
    #pragma unroll 8
    for(int kk = 0; kk < D_; ++kk){
        float hv = s_h[kk];
        aq = fmaf(hv, Wq[kk*D_ + o], aq);
        ak = fmaf(hv, Wk[kk*D_ + o], ak);
        av = fmaf(hv, Wv[kk*D_ + o], av);
    }
    const float scale = 0.17677669529663687f;  // 1/sqrt(32)
    QS[(size_t)bv*D_ + o] = aq * scale;
    KS[(size_t)bv*D_ + o] = ak * scale;
    MV[(size_t)bv*D_ + o] = av;
}

// ------------------------------- E[b,hh,v,u] = exp(A - rowmax(A over all u))
__global__ void k_attE(const float* __restrict__ QS, const float* __restrict__ KS,
                       float* __restrict__ E){
    int id = blockIdx.x;             // ((b*4+hh)*36+v)
    int v  = id % V_;
    int bh = id / V_;
    int hh = bh & 3, b = bh >> 2;
    int u = threadIdx.x;             // 0..63
    __shared__ float s_q[DK_];
    if(u < DK_) s_q[u] = QS[(size_t)(b*V_ + v)*D_ + hh*DK_ + u];
    __syncthreads();
    float a = -INFINITY;
    if(u < V_){
        a = 0.f;
        const float* kp = &KS[(size_t)(b*V_ + u)*D_ + hh*DK_];
        #pragma unroll
        for(int kk = 0; kk < DK_; ++kk) a = fmaf(s_q[kk], kp[kk], a);
    }
    float m = a;
    for(int off = 32; off > 0; off >>= 1) m = fmaxf(m, __shfl_xor(m, off));
    if(u < V_) E[(size_t)id*V_ + u] = expf(a - m);
}

// ---------------- per (b,t): v5[dd*36+v] = (sum_u em*w)/den + MV + PE (bf16)
// LDS layouts blocked by u4 = u/4 so all hot reads are float4:
//   s_tw2/s_cb2: [u4][dd][4]  (lanes on dd -> 16B-slot sequential, conflict-free)
//   s_em2:       [u4][hv][4]  (2 distinct addrs per wave -> broadcast)
__global__ __launch_bounds__(256,2) void k_v5(const int* __restrict__ mask,
        const float* __restrict__ Xtemp, const float* __restrict__ tempW,
        const float* __restrict__ CB, const float* __restrict__ E,
        const float* __restrict__ MV, const float* __restrict__ PE,
        bf16* __restrict__ V5){
    __shared__ __align__(16) float s_tw2[9*D_*4];    // 18 KB
    __shared__ __align__(16) float s_cb2[9*D_*4];    // 18 KB
    __shared__ __align__(16) float s_em2[9*144*4];   // 20.25 KB
    __shared__ float s_rden[144];
    __shared__ __align__(16) float s_xt[V_];
    __shared__ float s_mk[V_];
    int bt = blockIdx.x;
    int b = bt >> 8, t = bt & 255;
    int tid = threadIdx.x;
    if(tid < V_){
        s_xt[tid] = Xtemp[(t*B_ + b)*V_ + tid];
        s_mk[tid] = (float)mask[(t*B_ + b)*V_ + tid];
    }
    for(int i = tid; i < V_*D_; i += 256){
        int u = i >> 7, dd = i & 127;
        int idx = ((u >> 2)*D_ + dd)*4 + (u & 3);
        s_tw2[idx] = tempW[i];
        s_cb2[idx] = CB[(size_t)b*K1_ + i];
    }
    __syncthreads();                 // s_mk ready for em staging
    for(int i = tid; i < 144*V_; i += 256){
        int hv = i / V_, u = i - hv*V_;
        s_em2[((u >> 2)*144 + hv)*4 + (u & 3)] = E[(size_t)b*144*V_ + i] * s_mk[u];
    }
    __syncthreads();
    if(tid < 144){
        float den = 0.f;
        #pragma unroll
        for(int u = 0; u < V_; ++u) den += s_em2[((u>>2)*144 + tid)*4 + (u&3)];
        if(den == 0.0f){             // all-masked fallback: softmax over raw A
            den = 0.f;
            #pragma unroll
            for(int u = 0; u < V_; ++u){
                float e = E[(size_t)b*144*V_ + tid*V_ + u];
                s_em2[((u>>2)*144 + tid)*4 + (u&3)] = e;
                den += e;
            }
        }
        s_rden[tid] = 1.0f / den;
    }
    __syncthreads();

    int dd = tid & 127, half = tid >> 7;
    int hh = dd >> 5;
    int vbase = half * 18;
    int hvb = hh*V_ + vbase;
    float acc[18] = {};
    #pragma unroll
    for(int u4 = 0; u4 < 9; ++u4){
        float4 xt4 = *(const float4*)&s_xt[u4*4];
        float4 tw4 = *(const float4*)&s_tw2[(u4*D_ + dd)*4];
        float4 cb4 = *(const float4*)&s_cb2[(u4*D_ + dd)*4];
        float4 w4;
        w4.x = fmaf(xt4.x, tw4.x, cb4.x);
        w4.y = fmaf(xt4.y, tw4.y, cb4.y);
        w4.z = fmaf(xt4.z, tw4.z, cb4.z);
        w4.w = fmaf(xt4.w, tw4.w, cb4.w);
        #pragma unroll
        for(int v = 0; v < 18; ++v){
            float4 e4 = *(const float4*)&s_em2[(u4*144 + hvb + v)*4];
            acc[v] = fmaf(e4.x, w4.x, fmaf(e4.y, w4.y,
                     fmaf(e4.z, w4.z, fmaf(e4.w, w4.w, acc[v]))));
        }
    }
    float pe = PE[(size_t)bt*D_ + dd];
    size_t obase = (size_t)bt*K1_ + dd*V_ + vbase;   // even -> dword-aligned
    unsigned int* o32 = (unsigned int*)&V5[obase];
    #pragma unroll
    for(int v = 0; v < 18; v += 2){
        float r0 = fmaf(acc[v],   s_rden[hvb + v],
                        MV[((size_t)b*V_ + vbase + v)*D_ + dd] + pe);
        float r1 = fmaf(acc[v+1], s_rden[hvb + v + 1],
                        MV[((size_t)b*V_ + vbase + v + 1)*D_ + dd] + pe);
        o32[v >> 1] = (unsigned int)bf16_bits(r0) |
                      ((unsigned int)bf16_bits(r1) << 16);
    }
}

// ------------------------------------------- W1 (f32, N x K) -> bf16 (N x K)
__global__ void k_cast(const float* __restrict__ src, bf16* __restrict__ dst){
    int i = (blockIdx.x*256 + threadIdx.x)*4;   // n = 512*4608, exact
    float4 v = *(const float4*)&src[i];
    dst[i+0] = __float2bfloat16(v.x);
    dst[i+1] = __float2bfloat16(v.y);
    dst[i+2] = __float2bfloat16(v.z);
    dst[i+3] = __float2bfloat16(v.w);
}

// ---------------- y1 = V5(MxK bf16) @ W1^T(NxK bf16) + b1 ; MFMA 128x64 tile
// 1D grid of 512 with XCD-chunk swizzle: XCD x owns logical tiles [64x,64x+64)
// = 8 m-panels x all 8 n-blocks -> A-panel L2-resident per XCD.
__global__ __launch_bounds__(256) void k_gemm1(const bf16* __restrict__ A,
        const bf16* __restrict__ Bw, const float* __restrict__ bias,
        float* __restrict__ C){
    __shared__ __align__(16) bf16 As[128*32];    // 8 KB   [row][k], BK=32
    __shared__ __align__(16) bf16 Bs[64*32];     // 4 KB
    int bid = blockIdx.x;
    int L = (bid & 7)*64 + (bid >> 3);           // bijective, 512 % 8 == 0
    int nb = L & 7, mb = L >> 3;
    int m0 = mb * 128, n0 = nb * 64;
    int tid = threadIdx.x;
    int w = tid >> 6, l = tid & 63;
    int wr = w >> 1, wc = w & 1;                 // wave -> 64x32 sub-tile
    int r = l & 15, kg = l >> 4;
    f32x4 acc[4][2] = {};

    // staging: unit u covers row u>>2, k-part (u&3)*8 (16B per lane, linear LDS)
    int ua0 = w*64 + l;            // A rows 0..63
    int ua1 = (4+w)*64 + l;        // A rows 64..127
    const bf16* ga0 = A  + (size_t)(m0 + (ua0 >> 2))*K1_ + (ua0 & 3)*8;
    const bf16* ga1 = A  + (size_t)(m0 + (ua1 >> 2))*K1_ + (ua1 & 3)*8;
    const bf16* gb  = Bw + (size_t)(n0 + (ua0 >> 2))*K1_ + (ua0 & 3)*8;
    bf16* la0 = &As[(size_t)w*512];
    bf16* la1 = &As[(size_t)(4+w)*512];
    bf16* lb  = &Bs[(size_t)w*512];

    for(int k0 = 0; k0 < K1_; k0 += 32){
        GLD16(ga0 + k0, la0);
        GLD16(ga1 + k0, la1);
        GLD16(gb  + k0, lb);
        __syncthreads();           // drains vmcnt -> tile ready
        short8 af[4], bfr[2];
        #pragma unroll
        for(int m = 0; m < 4; ++m)
            af[m] = *(const short8*)&As[(wr*64 + m*16 + r)*32 + kg*8];
        #pragma unroll
        for(int n = 0; n < 2; ++n)
            bfr[n] = *(const short8*)&Bs[(wc*32 + n*16 + r)*32 + kg*8];
        #pragma unroll
        for(int m = 0; m < 4; ++m)
            #pragma unroll
            for(int n = 0; n < 2; ++n)
                acc[m][n] = __builtin_amdgcn_mfma_f32_16x16x32_bf16(
                                af[m], bfr[n], acc[m][n], 0, 0, 0);
        __syncthreads();
    }
    // C/D layout: col = lane&15, row = (lane>>4)*4 + i   [m89]
    #pragma unroll
    for(int m = 0; m < 4; ++m){
        int rowb = m0 + wr*64 + m*16 + kg*4;
        #pragma unroll
        for(int n = 0; n < 2; ++n){
            int col = n0 + wc*32 + n*16 + r;
            float bv = bias[col];
            #pragma unroll
            for(int i = 0; i < 4; ++i)
                C[(size_t)(rowb + i)*D4_ + col] = acc[m][n][i] + bv;
        }
    }
}

// -------------------------------------- per-channel sum / sumsq over M rows
__global__ void k_stats(const float* __restrict__ X, int C, float* __restrict__ ST){
    int r0 = blockIdx.x * 64;
    int tid = threadIdx.x;
    for(int c = tid; c < C; c += 256){
        float s = 0.f, q = 0.f;
        for(int r = 0; r < 64; ++r){
            float v = X[(size_t)(r0 + r)*C + c];
            s += v;
            q = fmaf(v, v, q);
        }
        atomicAdd(&ST[c], s);
        atomicAdd(&ST[C + c], q);
    }
}

__global__ void k_bnfin(const float* __restrict__ ST, const float* __restrict__ g,
                        const float* __restrict__ bb, int C, float* __restrict__ P){
    int c = blockIdx.x * blockDim.x + threadIdx.x;
    if(c < C){
        float mu  = ST[c] * (1.0f / M_);
        float var = ST[C + c] * (1.0f / M_) - mu*mu;
        float sc  = g[c] * rsqrtf(var + 1e-5f);
        P[c]     = sc;
        P[C + c] = bb[c] - mu*sc;
    }
}

// ---------------- y2 = gelu(BN1(y1)) @ W2^T + b2 ; 64x64 tile, BN+gelu on load
__global__ __launch_bounds__(256) void k_gemm2(const float* __restrict__ Y1,
        const float* __restrict__ P1, const float* __restrict__ W2,
        const float* __restrict__ b2, float* __restrict__ Z){
    __shared__ __align__(16) float As[16][68];
    __shared__ __align__(16) float Bs[16][68];
    int tid = threadIdx.x;
    int m0 = blockIdx.x * 64, n0 = blockIdx.y * 64;
    float acc[4][4] = {};
    int arow = tid >> 2, ac = (tid & 3) * 4;
    int ty = tid >> 4, tx = tid & 15;
    for(int k0 = 0; k0 < D4_; k0 += 16){
        float4 a = *(const float4*)&Y1[(size_t)(m0 + arow)*D4_ + k0 + ac];
        float4 w = *(const float4*)&W2[(size_t)(n0 + arow)*D4_ + k0 + ac];
        As[ac+0][arow] = gelu_f(fmaf(a.x, P1[k0+ac+0], P1[D4_ + k0+ac+0]));
        As[ac+1][arow] = gelu_f(fmaf(a.y, P1[k0+ac+1], P1[D4_ + k0+ac+1]));
        As[ac+2][arow] = gelu_f(fmaf(a.z, P1[k0+ac+2], P1[D4_ + k0+ac+2]));
        As[ac+3][arow] = gelu_f(fmaf(a.w, P1[k0+ac+3], P1[D4_ + k0+ac+3]));
        Bs[ac+0][arow] = w.x; Bs[ac+1][arow] = w.y;
        Bs[ac+2][arow] = w.z; Bs[ac+3][arow] = w.w;
        __syncthreads();
        #pragma unroll
        for(int kk = 0; kk < 16; ++kk){
            float4 x = *(const float4*)&As[kk][ty*4];
            float4 y = *(const float4*)&Bs[kk][tx*4];
            float av[4] = {x.x,x.y,x.z,x.w};
            float bv[4] = {y.x,y.y,y.z,y.w};
            #pragma unroll
            for(int i = 0; i < 4; ++i)
                #pragma unroll
                for(int j = 0; j < 4; ++j)
                    acc[i][j] = fmaf(av[i], bv[j], acc[i][j]);
        }
        __syncthreads();
    }
    #pragma unroll
    for(int i = 0; i < 4; ++i){
        int row = m0 + ty*4 + i, col = n0 + tx*4;
        float4 o;
        o.x = acc[i][0] + b2[col+0];
        o.y = acc[i][1] + b2[col+1];
        o.z = acc[i][2] + b2[col+2];
        o.w = acc[i][3] + b2[col+3];
        *(float4*)&Z[(size_t)row*D_ + col] = o;
    }
}

// ------- z = gelu(BN2(y2)); LN over d; out[b,o,t] = z + zn (t-contig float4)
__global__ __launch_bounds__(256) void k_final(const float* __restrict__ Z,
        const float* __restrict__ P2, const float* __restrict__ lng,
        const float* __restrict__ lnb, float* __restrict__ out){
    __shared__ float s_z[64*129];
    __shared__ float s_mu[64];
    __shared__ float s_rs[64];
    int b  = blockIdx.x >> 2;
    int t0 = (blockIdx.x & 3) * 64;
    int tid = threadIdx.x;
    #pragma unroll
    for(int i = 0; i < 32; ++i){
        int idx = tid + i*256;
        int row = idx >> 7, col = idx & 127;
        float v = Z[(size_t)(b*T_ + t0 + row)*D_ + col];
        s_z[row*129 + col] = gelu_f(fmaf(v, P2[col], P2[D_ + col]));
    }
    __syncthreads();
    if(tid < 64){
        float s = 0.f;
        #pragma unroll
        for(int j = 0; j < D_; ++j) s += s_z[tid*129 + j];
        float mu = s * (1.0f / D_);
        float q = 0.f;
        #pragma unroll
        for(int j = 0; j < D_; ++j){
            float dv = s_z[tid*129 + j] - mu;
            q = fmaf(dv, dv, q);
        }
        s_mu[tid] = mu;
        s_rs[tid] = rsqrtf(q * (1.0f / D_) + 1e-5f);
    }
    __syncthreads();
    int o  = tid & 127;
    int th = tid >> 7;               // 0/1 -> t-half of the 64-row tile
    float g  = lng[o];
    float be = lnb[o];
    #pragma unroll
    for(int j4 = 0; j4 < 8; ++j4){
        float4 ov;
        #pragma unroll
        for(int q = 0; q < 4; ++q){
            int tt = th*32 + j4*4 + q;
            float z = s_z[tt*129 + o];
            float zn = fmaf((z - s_mu[tt]) * s_rs[tt], g, be);
            (&ov.x)[q] = z + zn;
        }
        *(float4*)&out[((size_t)(b*D_ + o))*T_ + t0 + th*32 + j4*4] = ov;
    }
}

extern "C" void kernel_launch(void* const* d_in, const int* in_sizes, int n_in,
                              void* d_out, int out_size, void* d_ws, size_t ws_size,
                              hipStream_t stream){
    const float* Xtemp   = (const float*)d_in[0];
    const float* Xtimes  = (const float*)d_in[1];
    const float* Xstatic = (const float*)d_in[2];
    const int*   mask    = (const int*)  d_in[3];
    const float* Wq      = (const float*)d_in[4];
    const float* Wk      = (const float*)d_in[5];
    const float* Wv      = (const float*)d_in[6];
    const float* tempW   = (const float*)d_in[7];
    const float* tempB   = (const float*)d_in[8];
    const float* embW    = (const float*)d_in[9];
    const float* embB    = (const float*)d_in[10];
    const float* W1      = (const float*)d_in[11];
    const float* b1      = (const float*)d_in[12];
    const float* bn1g    = (const float*)d_in[13];
    const float* bn1b    = (const float*)d_in[14];
    const float* W2      = (const float*)d_in[15];
    const float* b2      = (const float*)d_in[16];
    const float* bn2g    = (const float*)d_in[17];
    const float* bn2b    = (const float*)d_in[18];
    const float* lng     = (const float*)d_in[19];
    const float* lnb     = (const float*)d_in[20];
    float* out = (float*)d_out;

    float* w = (float*)d_ws;
    float* PE = w;  w += (size_t)M_ * D_;          // 1,048,576 f32
    float* CB = w;  w += (size_t)B_ * V_ * D_;     // 147,456
    float* H4 = w;  w += (size_t)B_ * V_ * D_;
    float* QS = w;  w += (size_t)B_ * V_ * D_;
    float* KS = w;  w += (size_t)B_ * V_ * D_;
    float* MV = w;  w += (size_t)B_ * V_ * D_;
    float* E  = w;  w += (size_t)B_ * H_ * V_ * V_; // 165,888
    float* Y1 = w;  w += (size_t)M_ * D4_;          // 4,194,304
    float* Z1 = w;  w += (size_t)M_ * D_;           // 1,048,576
    float* ST1 = w; w += 1024;
    float* ST2 = w; w += 256;
    float* P1  = w; w += 1024;
    float* P2  = w; w += 256;
    bf16* V5  = (bf16*)w;                            // 75.5 MB
    bf16* W1b = (bf16*)(w + ((size_t)M_ * K1_) / 2); // 4.7 MB

    hipMemsetAsync(ST1, 0, (1024 + 256) * sizeof(float), stream);

    k_pe  <<<M_, D_, 0, stream>>>(Xtimes, PE);
    k_cb  <<<B_*V_, D_, 0, stream>>>(Xstatic, embW, embB, tempB, CB);
    k_cast<<<(D4_*K1_)/1024, 256, 0, stream>>>(W1, W1b);
    k_h4  <<<B_*V_, 256, 0, stream>>>(Xtemp, mask, PE, tempW, CB, H4);
    k_qkv <<<B_*V_, D_, 0, stream>>>(H4, Wq, Wk, Wv, QS, KS, MV);
    k_attE<<<B_*H_*V_, 64, 0, stream>>>(QS, KS, E);
    k_v5  <<<M_, 256, 0, stream>>>(mask, Xtemp, tempW, CB, E, MV, PE, V5);
    k_gemm1<<<512, 256, 0, stream>>>(V5, W1b, b1, Y1);
    k_stats<<<M_/64, 256, 0, stream>>>(Y1, D4_, ST1);
    k_bnfin<<<2, 256, 0, stream>>>(ST1, bn1g, bn1b, D4_, P1);
    k_gemm2<<<dim3(M_/64, D_/64), 256, 0, stream>>>(Y1, P1, W2, b2, Z1);
    k_stats<<<M_/64, 256, 0, stream>>>(Z1, D_, ST2);
    k_bnfin<<<1, 128, 0, stream>>>(ST2, bn2g, bn2b, D_, P2);
    k_final<<<B_*(T_/64), 256, 0, stream>>>(Z1, P2, lng, lnb, out);
}